// Round 2
// baseline (569.540 us; speedup 1.0000x reference)
//
#include <hip/hip_runtime.h>

#define NFEAT 96
#define DIM 64

// ---------------- CSR build ----------------

__global__ void k_hist(const int* __restrict__ tgt, int* __restrict__ cnt, int E) {
    int i = blockIdx.x * blockDim.x + threadIdx.x;
    int stride = gridDim.x * blockDim.x;
    for (; i < E; i += stride) atomicAdd(&cnt[tgt[i]], 1);
}

// Single-block exclusive scan over cnt[N] -> rowstart[N+1], wpos[N]=rowstart[N]
__global__ void k_scan(const int* __restrict__ cnt, int* __restrict__ rowstart,
                       int* __restrict__ wpos, int N) {
    __shared__ int sums[1024];
    const int t = threadIdx.x;
    const int per = (N + 1023) >> 10;
    const int s0 = t * per;
    const int s1 = min(s0 + per, N);
    int local = 0;
    for (int i = s0; i < s1; ++i) local += cnt[i];
    sums[t] = local;
    __syncthreads();
    // inclusive Hillis-Steele scan over 1024 partials
    for (int off = 1; off < 1024; off <<= 1) {
        int add = (t >= off) ? sums[t - off] : 0;
        __syncthreads();
        sums[t] += add;
        __syncthreads();
    }
    int run = (t == 0) ? 0 : sums[t - 1];
    for (int i = s0; i < s1; ++i) {
        rowstart[i] = run;
        wpos[i] = run;
        run += cnt[i];
    }
    if (t == 0) rowstart[N] = sums[1023];
}

__global__ void k_scatter(const int* __restrict__ src, const int* __restrict__ tgt,
                          int* __restrict__ wpos, int* __restrict__ csr_src, int E) {
    int i = blockIdx.x * blockDim.x + threadIdx.x;
    int stride = gridDim.x * blockDim.x;
    for (; i < E; i += stride) {
        int tg = tgt[i];
        int p = atomicAdd(&wpos[tg], 1);
        csr_src[p] = src[i];
    }
}

// ---------------- dual skinny GEMM: A = X@Wl, B = X@Wr + b ----------------
// X: [N,K] fp32 row-major, Wl/Wr: [K,DIM], b: [DIM].
// One wave handles 8 rows; lane = output column. W staged in LDS.
template <int K>
__global__ void k_mm(const float* __restrict__ X, const float* __restrict__ Wl,
                     const float* __restrict__ Wr, const float* __restrict__ b,
                     float* __restrict__ A, float* __restrict__ B, int N) {
    __shared__ float wl_s[K * DIM];
    __shared__ float wr_s[K * DIM];
    __shared__ float b_s[DIM];
    for (int i = threadIdx.x; i < K * DIM; i += blockDim.x) {
        wl_s[i] = Wl[i];
        wr_s[i] = Wr[i];
    }
    if (threadIdx.x < DIM) b_s[threadIdx.x] = b[threadIdx.x];
    __syncthreads();

    const int lane = threadIdx.x & 63;
    const int wave = blockIdx.x * (blockDim.x >> 6) + (threadIdx.x >> 6);
    const int nwaves = gridDim.x * (blockDim.x >> 6);
    constexpr int R = 8;

    for (int r0 = wave * R; r0 < N; r0 += nwaves * R) {
        const int rmax = min(R, N - r0);
        float accl[R], accr[R];
#pragma unroll
        for (int i = 0; i < R; ++i) { accl[i] = 0.f; accr[i] = 0.f; }

        for (int k = 0; k < K; k += 4) {
            const float wl0 = wl_s[(k + 0) * DIM + lane];
            const float wl1 = wl_s[(k + 1) * DIM + lane];
            const float wl2 = wl_s[(k + 2) * DIM + lane];
            const float wl3 = wl_s[(k + 3) * DIM + lane];
            const float wr0 = wr_s[(k + 0) * DIM + lane];
            const float wr1 = wr_s[(k + 1) * DIM + lane];
            const float wr2 = wr_s[(k + 2) * DIM + lane];
            const float wr3 = wr_s[(k + 3) * DIM + lane];
#pragma unroll
            for (int i = 0; i < R; ++i) {
                if (i < rmax) {
                    const float4 xv =
                        *reinterpret_cast<const float4*>(X + (size_t)(r0 + i) * K + k);
                    accl[i] = fmaf(xv.x, wl0, accl[i]);
                    accl[i] = fmaf(xv.y, wl1, accl[i]);
                    accl[i] = fmaf(xv.z, wl2, accl[i]);
                    accl[i] = fmaf(xv.w, wl3, accl[i]);
                    accr[i] = fmaf(xv.x, wr0, accr[i]);
                    accr[i] = fmaf(xv.y, wr1, accr[i]);
                    accr[i] = fmaf(xv.z, wr2, accr[i]);
                    accr[i] = fmaf(xv.w, wr3, accr[i]);
                }
            }
        }
#pragma unroll
        for (int i = 0; i < R; ++i) {
            if (i < rmax) {
                A[(size_t)(r0 + i) * DIM + lane] = accl[i];
                B[(size_t)(r0 + i) * DIM + lane] = accr[i] + b_s[lane];
            }
        }
    }
}

// ---------------- per-node aggregation: out = sum(A[src])/max(deg,1) + B ----------------
// One wave per node, lane = column.
template <bool RELU>
__global__ void k_aggr(const float* __restrict__ A, const float* __restrict__ B,
                       const int* __restrict__ rowstart, const int* __restrict__ csr_src,
                       float* __restrict__ out, int N) {
    const int lane = threadIdx.x & 63;
    const int wave = blockIdx.x * (blockDim.x >> 6) + (threadIdx.x >> 6);
    const int nwaves = gridDim.x * (blockDim.x >> 6);
    for (int n = wave; n < N; n += nwaves) {
        const int r0 = rowstart[n];
        const int r1 = rowstart[n + 1];
        float s = 0.f;
        int cur = (r0 < r1) ? csr_src[r0] : 0;
        for (int j = r0; j < r1; ++j) {
            // prefetch next src index while the A row load is in flight
            int nxt = (j + 1 < r1) ? csr_src[j + 1] : 0;
            s += A[(size_t)cur * DIM + lane];
            cur = nxt;
        }
        const float c = (float)(r1 - r0);
        float v = s / fmaxf(c, 1.f) + B[(size_t)n * DIM + lane];
        if (RELU) v = fmaxf(v, 0.f);
        out[(size_t)n * DIM + lane] = v;
    }
}

extern "C" void kernel_launch(void* const* d_in, const int* in_sizes, int n_in,
                              void* d_out, int out_size, void* d_ws, size_t ws_size,
                              hipStream_t stream) {
    const float* x   = (const float*)d_in[0];
    const int*   ei  = (const int*)d_in[1];
    const float* Wl1 = (const float*)d_in[2];
    const float* Wr1 = (const float*)d_in[3];
    const float* b1  = (const float*)d_in[4];
    const float* Wl2 = (const float*)d_in[5];
    const float* Wr2 = (const float*)d_in[6];
    const float* b2  = (const float*)d_in[7];
    float* out = (float*)d_out;

    const int N = in_sizes[0] / NFEAT;
    const int E = in_sizes[1] / 2;
    const int* src = ei;
    const int* tgt = ei + E;

    char* ws = (char*)d_ws;
    size_t off = 0;
    auto alloc = [&](size_t bytes) -> void* {
        void* p = ws + off;
        off = (off + bytes + 255) & ~(size_t)255;
        return p;
    };
    int*   cnt      = (int*)alloc((size_t)N * 4);
    int*   rowstart = (int*)alloc((size_t)(N + 1) * 4);
    int*   wpos     = (int*)alloc((size_t)N * 4);
    int*   csr      = (int*)alloc((size_t)E * 4);
    float* A        = (float*)alloc((size_t)N * DIM * 4);
    float* B        = (float*)alloc((size_t)N * DIM * 4);
    float* H        = (float*)alloc((size_t)N * DIM * 4);

    hipMemsetAsync(cnt, 0, (size_t)N * 4, stream);

    k_hist<<<2048, 256, 0, stream>>>(tgt, cnt, E);
    k_scan<<<1, 1024, 0, stream>>>(cnt, rowstart, wpos, N);
    k_scatter<<<2048, 256, 0, stream>>>(src, tgt, wpos, csr, E);

    const int mm_waves = (N + 7) / 8;
    const int mm_blocks = (mm_waves + 3) / 4;

    // layer 1: A = x@Wl1, B = x@Wr1 + b1 ; H = relu(aggr(A)/deg + B)
    k_mm<NFEAT><<<mm_blocks, 256, 0, stream>>>(x, Wl1, Wr1, b1, A, B, N);
    k_aggr<true><<<2048, 256, 0, stream>>>(A, B, rowstart, csr, H, N);

    // layer 2: A = H@Wl2, B = H@Wr2 + b2 ; out = aggr(A)/deg + B
    k_mm<DIM><<<mm_blocks, 256, 0, stream>>>(H, Wl2, Wr2, b2, A, B, N);
    k_aggr<false><<<2048, 256, 0, stream>>>(A, B, rowstart, csr, out, N);
}

// Round 8
// 299.833 us; speedup vs baseline: 1.8995x; 1.8995x over previous
//
#include <hip/hip_runtime.h>

#define NFEAT 96
#define DIM 64

// ---------------- CSR build ----------------

__global__ void k_hist(const int* __restrict__ tgt, int* __restrict__ cnt, int E) {
    int i = blockIdx.x * blockDim.x + threadIdx.x;
    int stride = gridDim.x * blockDim.x;
    for (; i < E; i += stride) atomicAdd(&cnt[tgt[i]], 1);
}

// ---- 3-phase scan: chunk=1024 elements per block, 256 threads, 4 per thread ----

// phase 1: per-chunk sums
__global__ void k_scan1(const int* __restrict__ cnt, int* __restrict__ bsum, int N) {
    __shared__ int ws[4];
    const int t = threadIdx.x;
    const int lane = t & 63, w = t >> 6;
    const int base = blockIdx.x * 1024 + t * 4;
    int s = 0;
    if (base + 3 < N) {
        int4 v = *reinterpret_cast<const int4*>(cnt + base);
        s = v.x + v.y + v.z + v.w;
    } else {
        for (int i = 0; i < 4; ++i)
            if (base + i < N) s += cnt[base + i];
    }
    for (int off = 32; off; off >>= 1) s += __shfl_down(s, off, 64);
    if (lane == 0) ws[w] = s;
    __syncthreads();
    if (t == 0) bsum[blockIdx.x] = ws[0] + ws[1] + ws[2] + ws[3];
}

// phase 2: exclusive scan of bsum[nb] -> boff[nb]; also rowstart[N] = total
__global__ void k_scan2(const int* __restrict__ bsum, int* __restrict__ boff,
                        int* __restrict__ rowstart, int nb, int N) {
    const int lane = threadIdx.x;  // 64 threads = 1 wave
    int carry = 0;
    for (int b0 = 0; b0 < nb; b0 += 64) {
        int i = b0 + lane;
        int orig = (i < nb) ? bsum[i] : 0;
        int v = orig;
        for (int off = 1; off < 64; off <<= 1) {
            int u = __shfl_up(v, off, 64);
            if (lane >= off) v += u;
        }
        if (i < nb) boff[i] = carry + v - orig;
        carry += __shfl(v, 63, 64);
    }
    if (lane == 0) rowstart[N] = carry;
}

// phase 3: per-chunk exclusive scan + chunk offset -> rowstart, wpos
__global__ void k_scan3(const int* __restrict__ cnt, const int* __restrict__ boff,
                        int* __restrict__ rowstart, int* __restrict__ wpos, int N) {
    __shared__ int wsum[4];
    const int t = threadIdx.x;
    const int lane = t & 63, w = t >> 6;
    const int base = blockIdx.x * 1024 + t * 4;
    int4 v = make_int4(0, 0, 0, 0);
    if (base + 3 < N) {
        v = *reinterpret_cast<const int4*>(cnt + base);
    } else {
        int* p = &v.x;
        for (int i = 0; i < 4; ++i)
            if (base + i < N) p[i] = cnt[base + i];
    }
    const int s = v.x + v.y + v.z + v.w;
    int inc = s;
    for (int off = 1; off < 64; off <<= 1) {
        int u = __shfl_up(inc, off, 64);
        if (lane >= off) inc += u;
    }
    if (lane == 63) wsum[w] = inc;
    __syncthreads();
    int woff = 0;
    for (int i = 0; i < w; ++i) woff += wsum[i];
    int r = boff[blockIdx.x] + woff + inc - s;
    if (base + 0 < N) { rowstart[base + 0] = r; wpos[base + 0] = r; } r += v.x;
    if (base + 1 < N) { rowstart[base + 1] = r; wpos[base + 1] = r; } r += v.y;
    if (base + 2 < N) { rowstart[base + 2] = r; wpos[base + 2] = r; } r += v.z;
    if (base + 3 < N) { rowstart[base + 3] = r; wpos[base + 3] = r; }
}

__global__ void k_scatter(const int* __restrict__ src, const int* __restrict__ tgt,
                          int* __restrict__ wpos, int* __restrict__ csr_src, int E) {
    int i = blockIdx.x * blockDim.x + threadIdx.x;
    int stride = gridDim.x * blockDim.x;
    for (; i < E; i += stride) {
        int tg = tgt[i];
        int p = atomicAdd(&wpos[tg], 1);
        csr_src[p] = src[i];
    }
}

// ---------------- dual skinny GEMM: A = X@Wl, B = X@Wr + b ----------------
// Block = 256 threads = 4 waves, 32 rows/block staged into LDS (coalesced).
// Wave w computes rows w*8..w*8+7; lane = output column. Weights read from
// global (L1/L2-hot: same 48KB for every block). One barrier, no loop.
template <int K>
__global__ __launch_bounds__(256) void k_mm(const float* __restrict__ X,
                                            const float* __restrict__ Wl,
                                            const float* __restrict__ Wr,
                                            const float* __restrict__ b,
                                            float* __restrict__ A,
                                            float* __restrict__ B, int N) {
    constexpr int ROWS = 32;
    __shared__ float xs[ROWS * K];  // K=96: 12KB, K=64: 8KB
    const int t = threadIdx.x;
    const int lane = t & 63;
    const int w = t >> 6;
    const int r0 = blockIdx.x * ROWS;
    const int nvalid = min(ROWS, N - r0);

    {
        const float4* src = reinterpret_cast<const float4*>(X + (size_t)r0 * K);
        float4* dst = reinterpret_cast<float4*>(xs);
        const int nv4 = (nvalid * K) >> 2;  // K%4==0
        for (int c = t; c < nv4; c += 256) dst[c] = src[c];
    }
    const float bias = b[lane];
    __syncthreads();

    const int rw = w * 8;
    float accl[8], accr[8];
#pragma unroll
    for (int i = 0; i < 8; ++i) { accl[i] = 0.f; accr[i] = 0.f; }

    for (int k = 0; k < K; k += 4) {
        const float wl0 = Wl[(k + 0) * DIM + lane];
        const float wl1 = Wl[(k + 1) * DIM + lane];
        const float wl2 = Wl[(k + 2) * DIM + lane];
        const float wl3 = Wl[(k + 3) * DIM + lane];
        const float wr0 = Wr[(k + 0) * DIM + lane];
        const float wr1 = Wr[(k + 1) * DIM + lane];
        const float wr2 = Wr[(k + 2) * DIM + lane];
        const float wr3 = Wr[(k + 3) * DIM + lane];
#pragma unroll
        for (int i = 0; i < 8; ++i) {
            const float4 xv = *reinterpret_cast<const float4*>(&xs[(rw + i) * K + k]);
            accl[i] = fmaf(xv.x, wl0, accl[i]);
            accl[i] = fmaf(xv.y, wl1, accl[i]);
            accl[i] = fmaf(xv.z, wl2, accl[i]);
            accl[i] = fmaf(xv.w, wl3, accl[i]);
            accr[i] = fmaf(xv.x, wr0, accr[i]);
            accr[i] = fmaf(xv.y, wr1, accr[i]);
            accr[i] = fmaf(xv.z, wr2, accr[i]);
            accr[i] = fmaf(xv.w, wr3, accr[i]);
        }
    }
#pragma unroll
    for (int i = 0; i < 8; ++i) {
        const int r = r0 + rw + i;
        if (r < N) {
            A[(size_t)r * DIM + lane] = accl[i];
            B[(size_t)r * DIM + lane] = accr[i] + bias;
        }
    }
}

// ---------------- per-node aggregation: out = sum(A[src])/max(deg,1) + B ----------------
// One wave per node, lane = column. 4-way unroll: 4 row-gathers + 4 index
// loads in flight per wave to cover L2/L3 latency (mean degree ~16).
template <bool RELU>
__global__ void k_aggr(const float* __restrict__ A, const float* __restrict__ Bm,
                       const int* __restrict__ rowstart, const int* __restrict__ csr_src,
                       float* __restrict__ out, int N) {
    const int lane = threadIdx.x & 63;
    const int wave = blockIdx.x * (blockDim.x >> 6) + (threadIdx.x >> 6);
    const int nwaves = gridDim.x * (blockDim.x >> 6);
    for (int n = wave; n < N; n += nwaves) {
        const int r0 = rowstart[n];
        const int r1 = rowstart[n + 1];
        float s0 = 0.f, s1 = 0.f, s2 = 0.f, s3 = 0.f;
        int j = r0;
        for (; j + 3 < r1; j += 4) {
            const int c0 = csr_src[j];
            const int c1 = csr_src[j + 1];
            const int c2 = csr_src[j + 2];
            const int c3 = csr_src[j + 3];
            s0 += A[(size_t)c0 * DIM + lane];
            s1 += A[(size_t)c1 * DIM + lane];
            s2 += A[(size_t)c2 * DIM + lane];
            s3 += A[(size_t)c3 * DIM + lane];
        }
        for (; j < r1; ++j) s0 += A[(size_t)csr_src[j] * DIM + lane];
        const float c = (float)(r1 - r0);
        float v = ((s0 + s1) + (s2 + s3)) / fmaxf(c, 1.f) + Bm[(size_t)n * DIM + lane];
        if (RELU) v = fmaxf(v, 0.f);
        out[(size_t)n * DIM + lane] = v;
    }
}

extern "C" void kernel_launch(void* const* d_in, const int* in_sizes, int n_in,
                              void* d_out, int out_size, void* d_ws, size_t ws_size,
                              hipStream_t stream) {
    const float* x   = (const float*)d_in[0];
    const int*   ei  = (const int*)d_in[1];
    const float* Wl1 = (const float*)d_in[2];
    const float* Wr1 = (const float*)d_in[3];
    const float* b1  = (const float*)d_in[4];
    const float* Wl2 = (const float*)d_in[5];
    const float* Wr2 = (const float*)d_in[6];
    const float* b2  = (const float*)d_in[7];
    float* out = (float*)d_out;

    const int N = in_sizes[0] / NFEAT;
    const int E = in_sizes[1] / 2;
    const int* src = ei;
    const int* tgt = ei + E;

    char* ws = (char*)d_ws;
    size_t off = 0;
    auto alloc = [&](size_t bytes) -> void* {
        void* p = ws + off;
        off = (off + bytes + 255) & ~(size_t)255;
        return p;
    };
    const int nb = (N + 1023) / 1024;
    int*   cnt      = (int*)alloc((size_t)N * 4);
    int*   rowstart = (int*)alloc((size_t)(N + 1) * 4);
    int*   wpos     = (int*)alloc((size_t)N * 4);
    int*   bsum     = (int*)alloc((size_t)nb * 4);
    int*   boff     = (int*)alloc((size_t)nb * 4);
    int*   csr      = (int*)alloc((size_t)E * 4);
    float* A        = (float*)alloc((size_t)N * DIM * 4);
    float* B        = (float*)alloc((size_t)N * DIM * 4);
    float* H        = (float*)alloc((size_t)N * DIM * 4);

    hipMemsetAsync(cnt, 0, (size_t)N * 4, stream);

    k_hist<<<2048, 256, 0, stream>>>(tgt, cnt, E);
    k_scan1<<<nb, 256, 0, stream>>>(cnt, bsum, N);
    k_scan2<<<1, 64, 0, stream>>>(bsum, boff, rowstart, nb, N);
    k_scan3<<<nb, 256, 0, stream>>>(cnt, boff, rowstart, wpos, N);
    k_scatter<<<2048, 256, 0, stream>>>(src, tgt, wpos, csr, E);

    const int mm_blocks = (N + 31) / 32;

    // layer 1: A = x@Wl1, B = x@Wr1 + b1 ; H = relu(aggr(A)/deg + B)
    k_mm<NFEAT><<<mm_blocks, 256, 0, stream>>>(x, Wl1, Wr1, b1, A, B, N);
    k_aggr<true><<<2048, 256, 0, stream>>>(A, B, rowstart, csr, H, N);

    // layer 2: A = H@Wl2, B = H@Wr2 + b2 ; out = aggr(A)/deg + B
    k_mm<DIM><<<mm_blocks, 256, 0, stream>>>(H, Wl2, Wr2, b2, A, B, N);
    k_aggr<false><<<2048, 256, 0, stream>>>(A, B, rowstart, csr, out, N);
}

// Round 10
// 279.951 us; speedup vs baseline: 2.0344x; 1.0710x over previous
//
#include <hip/hip_runtime.h>

#define NFEAT 96
#define DIM 64

// ---------------- CSR build ----------------

__global__ void k_hist(const int* __restrict__ tgt, int* __restrict__ cnt, int E) {
    int i = blockIdx.x * blockDim.x + threadIdx.x;
    int stride = gridDim.x * blockDim.x;
    for (; i < E; i += stride) atomicAdd(&cnt[tgt[i]], 1);
}

// ---- 3-phase scan: chunk=1024 elements per block, 256 threads, 4 per thread ----

// phase 1: per-chunk sums
__global__ void k_scan1(const int* __restrict__ cnt, int* __restrict__ bsum, int N) {
    __shared__ int ws[4];
    const int t = threadIdx.x;
    const int lane = t & 63, w = t >> 6;
    const int base = blockIdx.x * 1024 + t * 4;
    int s = 0;
    if (base + 3 < N) {
        int4 v = *reinterpret_cast<const int4*>(cnt + base);
        s = v.x + v.y + v.z + v.w;
    } else {
        for (int i = 0; i < 4; ++i)
            if (base + i < N) s += cnt[base + i];
    }
    for (int off = 32; off; off >>= 1) s += __shfl_down(s, off, 64);
    if (lane == 0) ws[w] = s;
    __syncthreads();
    if (t == 0) bsum[blockIdx.x] = ws[0] + ws[1] + ws[2] + ws[3];
}

// phase 2: exclusive scan of bsum[nb] -> boff[nb]; also rowstart[N] = total
__global__ void k_scan2(const int* __restrict__ bsum, int* __restrict__ boff,
                        int* __restrict__ rowstart, int nb, int N) {
    const int lane = threadIdx.x;  // 64 threads = 1 wave
    int carry = 0;
    for (int b0 = 0; b0 < nb; b0 += 64) {
        int i = b0 + lane;
        int orig = (i < nb) ? bsum[i] : 0;
        int v = orig;
        for (int off = 1; off < 64; off <<= 1) {
            int u = __shfl_up(v, off, 64);
            if (lane >= off) v += u;
        }
        if (i < nb) boff[i] = carry + v - orig;
        carry += __shfl(v, 63, 64);
    }
    if (lane == 0) rowstart[N] = carry;
}

// phase 3: per-chunk exclusive scan + chunk offset -> rowstart, wpos
__global__ void k_scan3(const int* __restrict__ cnt, const int* __restrict__ boff,
                        int* __restrict__ rowstart, int* __restrict__ wpos, int N) {
    __shared__ int wsum[4];
    const int t = threadIdx.x;
    const int lane = t & 63, w = t >> 6;
    const int base = blockIdx.x * 1024 + t * 4;
    int4 v = make_int4(0, 0, 0, 0);
    if (base + 3 < N) {
        v = *reinterpret_cast<const int4*>(cnt + base);
    } else {
        int* p = &v.x;
        for (int i = 0; i < 4; ++i)
            if (base + i < N) p[i] = cnt[base + i];
    }
    const int s = v.x + v.y + v.z + v.w;
    int inc = s;
    for (int off = 1; off < 64; off <<= 1) {
        int u = __shfl_up(inc, off, 64);
        if (lane >= off) inc += u;
    }
    if (lane == 63) wsum[w] = inc;
    __syncthreads();
    int woff = 0;
    for (int i = 0; i < w; ++i) woff += wsum[i];
    int r = boff[blockIdx.x] + woff + inc - s;
    if (base + 0 < N) { rowstart[base + 0] = r; wpos[base + 0] = r; } r += v.x;
    if (base + 1 < N) { rowstart[base + 1] = r; wpos[base + 1] = r; } r += v.y;
    if (base + 2 < N) { rowstart[base + 2] = r; wpos[base + 2] = r; } r += v.z;
    if (base + 3 < N) { rowstart[base + 3] = r; wpos[base + 3] = r; }
}

// Partitioned scatter: 8 node-range partitions; block-group (bid&7) handles
// only edges whose tgt is in its range. Round-robin block->XCD dispatch makes
// each partition's csr region XCD-local -> lines written by ONE L2, filled
// completely, written back once (was: 64B writeback per 4B write).
__global__ void k_scatter(const int* __restrict__ src, const int* __restrict__ tgt,
                          int* __restrict__ wpos, int* __restrict__ csr_src, int E,
                          int part_size) {
    const int part = blockIdx.x & 7;
    const int q = blockIdx.x >> 3;
    const int nq = gridDim.x >> 3;           // blocks per partition
    const int stride = nq * blockDim.x;      // threads per partition
    for (int i = q * blockDim.x + threadIdx.x; i < E; i += stride) {
        const int tg = tgt[i];
        if (tg / part_size == part) {
            const int p = atomicAdd(&wpos[tg], 1);
            csr_src[p] = src[i];
        }
    }
}

// ---------------- dual skinny GEMM: A = X@Wl, B = X@Wr + b ----------------
// Block = 256 threads = 4 waves, 32 rows/block staged into LDS (coalesced).
// Wave w computes rows w*8..w*8+7; lane = output column. Weights read from
// global (L1/L2-hot: same 48KB for every block). One barrier, no loop.
template <int K>
__global__ __launch_bounds__(256) void k_mm(const float* __restrict__ X,
                                            const float* __restrict__ Wl,
                                            const float* __restrict__ Wr,
                                            const float* __restrict__ b,
                                            float* __restrict__ A,
                                            float* __restrict__ B, int N) {
    constexpr int ROWS = 32;
    __shared__ float xs[ROWS * K];  // K=96: 12KB, K=64: 8KB
    const int t = threadIdx.x;
    const int lane = t & 63;
    const int w = t >> 6;
    const int r0 = blockIdx.x * ROWS;
    const int nvalid = min(ROWS, N - r0);

    {
        const float4* src = reinterpret_cast<const float4*>(X + (size_t)r0 * K);
        float4* dst = reinterpret_cast<float4*>(xs);
        const int nv4 = (nvalid * K) >> 2;  // K%4==0
        for (int c = t; c < nv4; c += 256) dst[c] = src[c];
    }
    const float bias = b[lane];
    __syncthreads();

    const int rw = w * 8;
    float accl[8], accr[8];
#pragma unroll
    for (int i = 0; i < 8; ++i) { accl[i] = 0.f; accr[i] = 0.f; }

    for (int k = 0; k < K; k += 4) {
        const float wl0 = Wl[(k + 0) * DIM + lane];
        const float wl1 = Wl[(k + 1) * DIM + lane];
        const float wl2 = Wl[(k + 2) * DIM + lane];
        const float wl3 = Wl[(k + 3) * DIM + lane];
        const float wr0 = Wr[(k + 0) * DIM + lane];
        const float wr1 = Wr[(k + 1) * DIM + lane];
        const float wr2 = Wr[(k + 2) * DIM + lane];
        const float wr3 = Wr[(k + 3) * DIM + lane];
#pragma unroll
        for (int i = 0; i < 8; ++i) {
            const float4 xv = *reinterpret_cast<const float4*>(&xs[(rw + i) * K + k]);
            accl[i] = fmaf(xv.x, wl0, accl[i]);
            accl[i] = fmaf(xv.y, wl1, accl[i]);
            accl[i] = fmaf(xv.z, wl2, accl[i]);
            accl[i] = fmaf(xv.w, wl3, accl[i]);
            accr[i] = fmaf(xv.x, wr0, accr[i]);
            accr[i] = fmaf(xv.y, wr1, accr[i]);
            accr[i] = fmaf(xv.z, wr2, accr[i]);
            accr[i] = fmaf(xv.w, wr3, accr[i]);
        }
    }
#pragma unroll
    for (int i = 0; i < 8; ++i) {
        const int r = r0 + rw + i;
        if (r < N) {
            A[(size_t)r * DIM + lane] = accl[i];
            B[(size_t)r * DIM + lane] = accr[i] + bias;
        }
    }
}

// ---------------- per-node aggregation: out = sum(A[src])/max(deg,1) + B ----------------
// One wave per node, lane = column. 4-way unroll: 4 row-gathers + 4 index
// loads in flight per wave to cover L2/L3 latency (mean degree ~16).
template <bool RELU>
__global__ void k_aggr(const float* __restrict__ A, const float* __restrict__ Bm,
                       const int* __restrict__ rowstart, const int* __restrict__ csr_src,
                       float* __restrict__ out, int N) {
    const int lane = threadIdx.x & 63;
    const int wave = blockIdx.x * (blockDim.x >> 6) + (threadIdx.x >> 6);
    const int nwaves = gridDim.x * (blockDim.x >> 6);
    for (int n = wave; n < N; n += nwaves) {
        const int r0 = rowstart[n];
        const int r1 = rowstart[n + 1];
        float s0 = 0.f, s1 = 0.f, s2 = 0.f, s3 = 0.f;
        int j = r0;
        for (; j + 3 < r1; j += 4) {
            const int c0 = csr_src[j];
            const int c1 = csr_src[j + 1];
            const int c2 = csr_src[j + 2];
            const int c3 = csr_src[j + 3];
            s0 += A[(size_t)c0 * DIM + lane];
            s1 += A[(size_t)c1 * DIM + lane];
            s2 += A[(size_t)c2 * DIM + lane];
            s3 += A[(size_t)c3 * DIM + lane];
        }
        for (; j < r1; ++j) s0 += A[(size_t)csr_src[j] * DIM + lane];
        const float c = (float)(r1 - r0);
        float v = ((s0 + s1) + (s2 + s3)) / fmaxf(c, 1.f) + Bm[(size_t)n * DIM + lane];
        if (RELU) v = fmaxf(v, 0.f);
        out[(size_t)n * DIM + lane] = v;
    }
}

extern "C" void kernel_launch(void* const* d_in, const int* in_sizes, int n_in,
                              void* d_out, int out_size, void* d_ws, size_t ws_size,
                              hipStream_t stream) {
    const float* x   = (const float*)d_in[0];
    const int*   ei  = (const int*)d_in[1];
    const float* Wl1 = (const float*)d_in[2];
    const float* Wr1 = (const float*)d_in[3];
    const float* b1  = (const float*)d_in[4];
    const float* Wl2 = (const float*)d_in[5];
    const float* Wr2 = (const float*)d_in[6];
    const float* b2  = (const float*)d_in[7];
    float* out = (float*)d_out;

    const int N = in_sizes[0] / NFEAT;
    const int E = in_sizes[1] / 2;
    const int* src = ei;
    const int* tgt = ei + E;

    char* ws = (char*)d_ws;
    size_t off = 0;
    auto alloc = [&](size_t bytes) -> void* {
        void* p = ws + off;
        off = (off + bytes + 255) & ~(size_t)255;
        return p;
    };
    const int nb = (N + 1023) / 1024;
    int*   cnt      = (int*)alloc((size_t)N * 4);
    int*   rowstart = (int*)alloc((size_t)(N + 1) * 4);
    int*   wpos     = (int*)alloc((size_t)N * 4);
    int*   bsum     = (int*)alloc((size_t)nb * 4);
    int*   boff     = (int*)alloc((size_t)nb * 4);
    int*   csr      = (int*)alloc((size_t)E * 4);
    float* A        = (float*)alloc((size_t)N * DIM * 4);
    float* B        = (float*)alloc((size_t)N * DIM * 4);
    float* H        = (float*)alloc((size_t)N * DIM * 4);

    hipMemsetAsync(cnt, 0, (size_t)N * 4, stream);

    k_hist<<<2048, 256, 0, stream>>>(tgt, cnt, E);
    k_scan1<<<nb, 256, 0, stream>>>(cnt, bsum, N);
    k_scan2<<<1, 64, 0, stream>>>(bsum, boff, rowstart, nb, N);
    k_scan3<<<nb, 256, 0, stream>>>(cnt, boff, rowstart, wpos, N);
    const int part_size = (N + 7) / 8;
    k_scatter<<<2048, 256, 0, stream>>>(src, tgt, wpos, csr, E, part_size);

    const int mm_blocks = (N + 31) / 32;

    // layer 1: A = x@Wl1, B = x@Wr1 + b1 ; H = relu(aggr(A)/deg + B)
    k_mm<NFEAT><<<mm_blocks, 256, 0, stream>>>(x, Wl1, Wr1, b1, A, B, N);
    k_aggr<true><<<2048, 256, 0, stream>>>(A, B, rowstart, csr, H, N);

    // layer 2: A = H@Wl2, B = H@Wr2 + b2 ; out = aggr(A)/deg + B
    k_mm<DIM><<<mm_blocks, 256, 0, stream>>>(H, Wl2, Wr2, b2, A, B, N);
    k_aggr<false><<<2048, 256, 0, stream>>>(A, B, rowstart, csr, out, N);
}

// Round 12
// 273.203 us; speedup vs baseline: 2.0847x; 1.0247x over previous
//
#include <hip/hip_runtime.h>
#include <hip/hip_bf16.h>

#define NFEAT 96
#define DIM 64

// ---------------- CSR build ----------------

// Partitioned histogram (same 8-way node-range trick as k_scatter): group
// (bid&7) only atomics cnt entries in its node range -> atomic traffic for
// each cnt line concentrated on one XCD. Costs an 8x re-read of tgt (L2/L3).
__global__ void k_hist(const int* __restrict__ tgt, int* __restrict__ cnt, int E,
                       int part_size) {
    const int part = blockIdx.x & 7;
    const int q = blockIdx.x >> 3;
    const int nq = gridDim.x >> 3;
    const int stride = nq * blockDim.x;
    for (int i = q * blockDim.x + threadIdx.x; i < E; i += stride) {
        const int tg = tgt[i];
        if (tg / part_size == part) atomicAdd(&cnt[tg], 1);
    }
}

// ---- 3-phase scan: chunk=1024 elements per block, 256 threads, 4 per thread ----

// phase 1: per-chunk sums
__global__ void k_scan1(const int* __restrict__ cnt, int* __restrict__ bsum, int N) {
    __shared__ int ws[4];
    const int t = threadIdx.x;
    const int lane = t & 63, w = t >> 6;
    const int base = blockIdx.x * 1024 + t * 4;
    int s = 0;
    if (base + 3 < N) {
        int4 v = *reinterpret_cast<const int4*>(cnt + base);
        s = v.x + v.y + v.z + v.w;
    } else {
        for (int i = 0; i < 4; ++i)
            if (base + i < N) s += cnt[base + i];
    }
    for (int off = 32; off; off >>= 1) s += __shfl_down(s, off, 64);
    if (lane == 0) ws[w] = s;
    __syncthreads();
    if (t == 0) bsum[blockIdx.x] = ws[0] + ws[1] + ws[2] + ws[3];
}

// phase 2: exclusive scan of bsum[nb] -> boff[nb]; also rowstart[N] = total
__global__ void k_scan2(const int* __restrict__ bsum, int* __restrict__ boff,
                        int* __restrict__ rowstart, int nb, int N) {
    const int lane = threadIdx.x;  // 64 threads = 1 wave
    int carry = 0;
    for (int b0 = 0; b0 < nb; b0 += 64) {
        int i = b0 + lane;
        int orig = (i < nb) ? bsum[i] : 0;
        int v = orig;
        for (int off = 1; off < 64; off <<= 1) {
            int u = __shfl_up(v, off, 64);
            if (lane >= off) v += u;
        }
        if (i < nb) boff[i] = carry + v - orig;
        carry += __shfl(v, 63, 64);
    }
    if (lane == 0) rowstart[N] = carry;
}

// phase 3: per-chunk exclusive scan + chunk offset -> rowstart, wpos
__global__ void k_scan3(const int* __restrict__ cnt, const int* __restrict__ boff,
                        int* __restrict__ rowstart, int* __restrict__ wpos, int N) {
    __shared__ int wsum[4];
    const int t = threadIdx.x;
    const int lane = t & 63, w = t >> 6;
    const int base = blockIdx.x * 1024 + t * 4;
    int4 v = make_int4(0, 0, 0, 0);
    if (base + 3 < N) {
        v = *reinterpret_cast<const int4*>(cnt + base);
    } else {
        int* p = &v.x;
        for (int i = 0; i < 4; ++i)
            if (base + i < N) p[i] = cnt[base + i];
    }
    const int s = v.x + v.y + v.z + v.w;
    int inc = s;
    for (int off = 1; off < 64; off <<= 1) {
        int u = __shfl_up(inc, off, 64);
        if (lane >= off) inc += u;
    }
    if (lane == 63) wsum[w] = inc;
    __syncthreads();
    int woff = 0;
    for (int i = 0; i < w; ++i) woff += wsum[i];
    int r = boff[blockIdx.x] + woff + inc - s;
    if (base + 0 < N) { rowstart[base + 0] = r; wpos[base + 0] = r; } r += v.x;
    if (base + 1 < N) { rowstart[base + 1] = r; wpos[base + 1] = r; } r += v.y;
    if (base + 2 < N) { rowstart[base + 2] = r; wpos[base + 2] = r; } r += v.z;
    if (base + 3 < N) { rowstart[base + 3] = r; wpos[base + 3] = r; }
}

// Partitioned scatter: 8 node-range partitions; block-group (bid&7) handles
// only edges whose tgt is in its range. Round-robin block->XCD dispatch makes
// each partition's csr region XCD-local -> lines written by ONE L2, filled
// completely, written back once (was: 64B writeback per 4B write).
__global__ void k_scatter(const int* __restrict__ src, const int* __restrict__ tgt,
                          int* __restrict__ wpos, int* __restrict__ csr_src, int E,
                          int part_size) {
    const int part = blockIdx.x & 7;
    const int q = blockIdx.x >> 3;
    const int nq = gridDim.x >> 3;           // blocks per partition
    const int stride = nq * blockDim.x;      // threads per partition
    for (int i = q * blockDim.x + threadIdx.x; i < E; i += stride) {
        const int tg = tgt[i];
        if (tg / part_size == part) {
            const int p = atomicAdd(&wpos[tg], 1);
            csr_src[p] = src[i];
        }
    }
}

// ---------------- dual skinny GEMM: A(bf16) = X@Wl, B(f32) = X@Wr + b ----------------
// Block = 256 threads = 4 waves, 32 rows/block staged into LDS (coalesced).
// Wave w computes rows w*8..w*8+7; lane = output column. Weights read from
// global (L1/L2-hot: same 48KB for every block). A is stored bf16: it is only
// consumed by the gather-sum in k_aggr, halving that kernel's read traffic.
template <int K>
__global__ __launch_bounds__(256) void k_mm(const float* __restrict__ X,
                                            const float* __restrict__ Wl,
                                            const float* __restrict__ Wr,
                                            const float* __restrict__ b,
                                            __hip_bfloat16* __restrict__ A,
                                            float* __restrict__ B, int N) {
    constexpr int ROWS = 32;
    __shared__ float xs[ROWS * K];  // K=96: 12KB, K=64: 8KB
    const int t = threadIdx.x;
    const int lane = t & 63;
    const int w = t >> 6;
    const int r0 = blockIdx.x * ROWS;
    const int nvalid = min(ROWS, N - r0);

    {
        const float4* src = reinterpret_cast<const float4*>(X + (size_t)r0 * K);
        float4* dst = reinterpret_cast<float4*>(xs);
        const int nv4 = (nvalid * K) >> 2;  // K%4==0
        for (int c = t; c < nv4; c += 256) dst[c] = src[c];
    }
    const float bias = b[lane];
    __syncthreads();

    const int rw = w * 8;
    float accl[8], accr[8];
#pragma unroll
    for (int i = 0; i < 8; ++i) { accl[i] = 0.f; accr[i] = 0.f; }

    for (int k = 0; k < K; k += 4) {
        const float wl0 = Wl[(k + 0) * DIM + lane];
        const float wl1 = Wl[(k + 1) * DIM + lane];
        const float wl2 = Wl[(k + 2) * DIM + lane];
        const float wl3 = Wl[(k + 3) * DIM + lane];
        const float wr0 = Wr[(k + 0) * DIM + lane];
        const float wr1 = Wr[(k + 1) * DIM + lane];
        const float wr2 = Wr[(k + 2) * DIM + lane];
        const float wr3 = Wr[(k + 3) * DIM + lane];
#pragma unroll
        for (int i = 0; i < 8; ++i) {
            const float4 xv = *reinterpret_cast<const float4*>(&xs[(rw + i) * K + k]);
            accl[i] = fmaf(xv.x, wl0, accl[i]);
            accl[i] = fmaf(xv.y, wl1, accl[i]);
            accl[i] = fmaf(xv.z, wl2, accl[i]);
            accl[i] = fmaf(xv.w, wl3, accl[i]);
            accr[i] = fmaf(xv.x, wr0, accr[i]);
            accr[i] = fmaf(xv.y, wr1, accr[i]);
            accr[i] = fmaf(xv.z, wr2, accr[i]);
            accr[i] = fmaf(xv.w, wr3, accr[i]);
        }
    }
#pragma unroll
    for (int i = 0; i < 8; ++i) {
        const int r = r0 + rw + i;
        if (r < N) {
            A[(size_t)r * DIM + lane] = __float2bfloat16(accl[i]);
            B[(size_t)r * DIM + lane] = accr[i] + bias;
        }
    }
}

// ---------------- per-node aggregation: out = sum(A[src])/max(deg,1) + B ----------------
// One wave per node, lane = column. A is bf16 (128B/row, one line per gather).
// 4-way unroll: 4 row-gathers + index loads in flight (mean degree ~16).
template <bool RELU>
__global__ void k_aggr(const __hip_bfloat16* __restrict__ A, const float* __restrict__ Bm,
                       const int* __restrict__ rowstart, const int* __restrict__ csr_src,
                       float* __restrict__ out, int N) {
    const int lane = threadIdx.x & 63;
    const int wave = blockIdx.x * (blockDim.x >> 6) + (threadIdx.x >> 6);
    const int nwaves = gridDim.x * (blockDim.x >> 6);
    for (int n = wave; n < N; n += nwaves) {
        const int r0 = rowstart[n];
        const int r1 = rowstart[n + 1];
        float s0 = 0.f, s1 = 0.f, s2 = 0.f, s3 = 0.f;
        int j = r0;
        for (; j + 3 < r1; j += 4) {
            const int c0 = csr_src[j];
            const int c1 = csr_src[j + 1];
            const int c2 = csr_src[j + 2];
            const int c3 = csr_src[j + 3];
            s0 += __bfloat162float(A[(size_t)c0 * DIM + lane]);
            s1 += __bfloat162float(A[(size_t)c1 * DIM + lane]);
            s2 += __bfloat162float(A[(size_t)c2 * DIM + lane]);
            s3 += __bfloat162float(A[(size_t)c3 * DIM + lane]);
        }
        for (; j < r1; ++j) s0 += __bfloat162float(A[(size_t)csr_src[j] * DIM + lane]);
        const float c = (float)(r1 - r0);
        float v = ((s0 + s1) + (s2 + s3)) / fmaxf(c, 1.f) + Bm[(size_t)n * DIM + lane];
        if (RELU) v = fmaxf(v, 0.f);
        out[(size_t)n * DIM + lane] = v;
    }
}

extern "C" void kernel_launch(void* const* d_in, const int* in_sizes, int n_in,
                              void* d_out, int out_size, void* d_ws, size_t ws_size,
                              hipStream_t stream) {
    const float* x   = (const float*)d_in[0];
    const int*   ei  = (const int*)d_in[1];
    const float* Wl1 = (const float*)d_in[2];
    const float* Wr1 = (const float*)d_in[3];
    const float* b1  = (const float*)d_in[4];
    const float* Wl2 = (const float*)d_in[5];
    const float* Wr2 = (const float*)d_in[6];
    const float* b2  = (const float*)d_in[7];
    float* out = (float*)d_out;

    const int N = in_sizes[0] / NFEAT;
    const int E = in_sizes[1] / 2;
    const int* src = ei;
    const int* tgt = ei + E;

    char* ws = (char*)d_ws;
    size_t off = 0;
    auto alloc = [&](size_t bytes) -> void* {
        void* p = ws + off;
        off = (off + bytes + 255) & ~(size_t)255;
        return p;
    };
    const int nb = (N + 1023) / 1024;
    int*   cnt      = (int*)alloc((size_t)N * 4);
    int*   rowstart = (int*)alloc((size_t)(N + 1) * 4);
    int*   wpos     = (int*)alloc((size_t)N * 4);
    int*   bsum     = (int*)alloc((size_t)nb * 4);
    int*   boff     = (int*)alloc((size_t)nb * 4);
    int*   csr      = (int*)alloc((size_t)E * 4);
    __hip_bfloat16* A = (__hip_bfloat16*)alloc((size_t)N * DIM * 2);
    float* B        = (float*)alloc((size_t)N * DIM * 4);
    float* H        = (float*)alloc((size_t)N * DIM * 4);

    hipMemsetAsync(cnt, 0, (size_t)N * 4, stream);

    const int part_size = (N + 7) / 8;
    k_hist<<<2048, 256, 0, stream>>>(tgt, cnt, E, part_size);
    k_scan1<<<nb, 256, 0, stream>>>(cnt, bsum, N);
    k_scan2<<<1, 64, 0, stream>>>(bsum, boff, rowstart, nb, N);
    k_scan3<<<nb, 256, 0, stream>>>(cnt, boff, rowstart, wpos, N);
    k_scatter<<<2048, 256, 0, stream>>>(src, tgt, wpos, csr, E, part_size);

    const int mm_blocks = (N + 31) / 32;

    // layer 1: A = x@Wl1 (bf16), B = x@Wr1 + b1 ; H = relu(aggr(A)/deg + B)
    k_mm<NFEAT><<<mm_blocks, 256, 0, stream>>>(x, Wl1, Wr1, b1, A, B, N);
    k_aggr<true><<<2048, 256, 0, stream>>>(A, B, rowstart, csr, H, N);

    // layer 2: A = H@Wl2 (bf16), B = H@Wr2 + b2 ; out = aggr(A)/deg + B
    k_mm<DIM><<<mm_blocks, 256, 0, stream>>>(H, Wl2, Wr2, b2, A, B, N);
    k_aggr<false><<<2048, 256, 0, stream>>>(A, B, rowstart, csr, out, N);
}

// Round 13
// 264.834 us; speedup vs baseline: 2.1506x; 1.0316x over previous
//
#include <hip/hip_runtime.h>
#include <hip/hip_bf16.h>

#define NFEAT 96
#define DIM 64

// ---------------- fused: dual skinny GEMM (layer 1) + partitioned histogram ----------------
// Blocks [0, mmB): mm.  Blocks [mmB, mmB+histB): histogram.  The two tasks are
// independent -> no sync needed; latency-bound hist atomics overlap with
// compute-bound mm on the same grid. mmB is a multiple of 8 so hist blocks'
// (bid&7) XCD-partition alignment is preserved.
template <int K>
__global__ __launch_bounds__(256) void k_mm_hist(const float* __restrict__ X,
                                                 const float* __restrict__ Wl,
                                                 const float* __restrict__ Wr,
                                                 const float* __restrict__ b,
                                                 __hip_bfloat16* __restrict__ A,
                                                 __hip_bfloat16* __restrict__ B, int N,
                                                 const int* __restrict__ tgt,
                                                 int* __restrict__ cnt, int E,
                                                 int part_size, int mmB) {
    constexpr int ROWS = 32;
    __shared__ float xs[ROWS * K];
    const int t = threadIdx.x;

    if ((int)blockIdx.x >= mmB) {
        // ---- histogram branch ----
        const int part = blockIdx.x & 7;                   // global bid -> XCD alignment
        const int hb = blockIdx.x - mmB;                   // mmB%8==0 -> hb&7 == bid&7
        const int q = hb >> 3;
        const int nq = (gridDim.x - mmB) >> 3;
        const int stride = nq * blockDim.x;
        for (int i = q * blockDim.x + t; i < E; i += stride) {
            const int tg = tgt[i];
            if (tg / part_size == part) atomicAdd(&cnt[tg], 1);
        }
        return;
    }

    // ---- mm branch ----
    const int lane = t & 63;
    const int w = t >> 6;
    const int r0 = blockIdx.x * ROWS;
    const int nvalid = min(ROWS, N - r0);

    if (nvalid > 0) {
        const float4* src = reinterpret_cast<const float4*>(X + (size_t)r0 * K);
        float4* dst = reinterpret_cast<float4*>(xs);
        const int nv4 = (nvalid * K) >> 2;
        for (int c = t; c < nv4; c += 256) dst[c] = src[c];
    }
    const float bias = b[lane];
    __syncthreads();
    if (nvalid <= 0) return;

    const int rw = w * 8;
    float accl[8], accr[8];
#pragma unroll
    for (int i = 0; i < 8; ++i) { accl[i] = 0.f; accr[i] = 0.f; }

    for (int k = 0; k < K; k += 4) {
        const float wl0 = Wl[(k + 0) * DIM + lane];
        const float wl1 = Wl[(k + 1) * DIM + lane];
        const float wl2 = Wl[(k + 2) * DIM + lane];
        const float wl3 = Wl[(k + 3) * DIM + lane];
        const float wr0 = Wr[(k + 0) * DIM + lane];
        const float wr1 = Wr[(k + 1) * DIM + lane];
        const float wr2 = Wr[(k + 2) * DIM + lane];
        const float wr3 = Wr[(k + 3) * DIM + lane];
#pragma unroll
        for (int i = 0; i < 8; ++i) {
            const float4 xv = *reinterpret_cast<const float4*>(&xs[(rw + i) * K + k]);
            accl[i] = fmaf(xv.x, wl0, accl[i]);
            accl[i] = fmaf(xv.y, wl1, accl[i]);
            accl[i] = fmaf(xv.z, wl2, accl[i]);
            accl[i] = fmaf(xv.w, wl3, accl[i]);
            accr[i] = fmaf(xv.x, wr0, accr[i]);
            accr[i] = fmaf(xv.y, wr1, accr[i]);
            accr[i] = fmaf(xv.z, wr2, accr[i]);
            accr[i] = fmaf(xv.w, wr3, accr[i]);
        }
    }
#pragma unroll
    for (int i = 0; i < 8; ++i) {
        const int r = r0 + rw + i;
        if (r < N) {
            A[(size_t)r * DIM + lane] = __float2bfloat16(accl[i]);
            B[(size_t)r * DIM + lane] = __float2bfloat16(accr[i] + bias);
        }
    }
}

// plain dual GEMM (layer 2)
template <int K>
__global__ __launch_bounds__(256) void k_mm(const float* __restrict__ X,
                                            const float* __restrict__ Wl,
                                            const float* __restrict__ Wr,
                                            const float* __restrict__ b,
                                            __hip_bfloat16* __restrict__ A,
                                            __hip_bfloat16* __restrict__ B, int N) {
    constexpr int ROWS = 32;
    __shared__ float xs[ROWS * K];
    const int t = threadIdx.x;
    const int lane = t & 63;
    const int w = t >> 6;
    const int r0 = blockIdx.x * ROWS;
    const int nvalid = min(ROWS, N - r0);

    {
        const float4* src = reinterpret_cast<const float4*>(X + (size_t)r0 * K);
        float4* dst = reinterpret_cast<float4*>(xs);
        const int nv4 = (nvalid * K) >> 2;
        for (int c = t; c < nv4; c += 256) dst[c] = src[c];
    }
    const float bias = b[lane];
    __syncthreads();

    const int rw = w * 8;
    float accl[8], accr[8];
#pragma unroll
    for (int i = 0; i < 8; ++i) { accl[i] = 0.f; accr[i] = 0.f; }

    for (int k = 0; k < K; k += 4) {
        const float wl0 = Wl[(k + 0) * DIM + lane];
        const float wl1 = Wl[(k + 1) * DIM + lane];
        const float wl2 = Wl[(k + 2) * DIM + lane];
        const float wl3 = Wl[(k + 3) * DIM + lane];
        const float wr0 = Wr[(k + 0) * DIM + lane];
        const float wr1 = Wr[(k + 1) * DIM + lane];
        const float wr2 = Wr[(k + 2) * DIM + lane];
        const float wr3 = Wr[(k + 3) * DIM + lane];
#pragma unroll
        for (int i = 0; i < 8; ++i) {
            const float4 xv = *reinterpret_cast<const float4*>(&xs[(rw + i) * K + k]);
            accl[i] = fmaf(xv.x, wl0, accl[i]);
            accl[i] = fmaf(xv.y, wl1, accl[i]);
            accl[i] = fmaf(xv.z, wl2, accl[i]);
            accl[i] = fmaf(xv.w, wl3, accl[i]);
            accr[i] = fmaf(xv.x, wr0, accr[i]);
            accr[i] = fmaf(xv.y, wr1, accr[i]);
            accr[i] = fmaf(xv.z, wr2, accr[i]);
            accr[i] = fmaf(xv.w, wr3, accr[i]);
        }
    }
#pragma unroll
    for (int i = 0; i < 8; ++i) {
        const int r = r0 + rw + i;
        if (r < N) {
            A[(size_t)r * DIM + lane] = __float2bfloat16(accl[i]);
            B[(size_t)r * DIM + lane] = __float2bfloat16(accr[i] + bias);
        }
    }
}

// ---- 3-phase scan: chunk=1024 elements per block, 256 threads, 4 per thread ----

__global__ void k_scan1(const int* __restrict__ cnt, int* __restrict__ bsum, int N) {
    __shared__ int ws[4];
    const int t = threadIdx.x;
    const int lane = t & 63, w = t >> 6;
    const int base = blockIdx.x * 1024 + t * 4;
    int s = 0;
    if (base + 3 < N) {
        int4 v = *reinterpret_cast<const int4*>(cnt + base);
        s = v.x + v.y + v.z + v.w;
    } else {
        for (int i = 0; i < 4; ++i)
            if (base + i < N) s += cnt[base + i];
    }
    for (int off = 32; off; off >>= 1) s += __shfl_down(s, off, 64);
    if (lane == 0) ws[w] = s;
    __syncthreads();
    if (t == 0) bsum[blockIdx.x] = ws[0] + ws[1] + ws[2] + ws[3];
}

__global__ void k_scan2(const int* __restrict__ bsum, int* __restrict__ boff,
                        int* __restrict__ rowstart, int nb, int N) {
    const int lane = threadIdx.x;  // 64 threads = 1 wave
    int carry = 0;
    for (int b0 = 0; b0 < nb; b0 += 64) {
        int i = b0 + lane;
        int orig = (i < nb) ? bsum[i] : 0;
        int v = orig;
        for (int off = 1; off < 64; off <<= 1) {
            int u = __shfl_up(v, off, 64);
            if (lane >= off) v += u;
        }
        if (i < nb) boff[i] = carry + v - orig;
        carry += __shfl(v, 63, 64);
    }
    if (lane == 0) rowstart[N] = carry;
}

__global__ void k_scan3(const int* __restrict__ cnt, const int* __restrict__ boff,
                        int* __restrict__ rowstart, int* __restrict__ wpos, int N) {
    __shared__ int wsum[4];
    const int t = threadIdx.x;
    const int lane = t & 63, w = t >> 6;
    const int base = blockIdx.x * 1024 + t * 4;
    int4 v = make_int4(0, 0, 0, 0);
    if (base + 3 < N) {
        v = *reinterpret_cast<const int4*>(cnt + base);
    } else {
        int* p = &v.x;
        for (int i = 0; i < 4; ++i)
            if (base + i < N) p[i] = cnt[base + i];
    }
    const int s = v.x + v.y + v.z + v.w;
    int inc = s;
    for (int off = 1; off < 64; off <<= 1) {
        int u = __shfl_up(inc, off, 64);
        if (lane >= off) inc += u;
    }
    if (lane == 63) wsum[w] = inc;
    __syncthreads();
    int woff = 0;
    for (int i = 0; i < w; ++i) woff += wsum[i];
    int r = boff[blockIdx.x] + woff + inc - s;
    if (base + 0 < N) { rowstart[base + 0] = r; wpos[base + 0] = r; } r += v.x;
    if (base + 1 < N) { rowstart[base + 1] = r; wpos[base + 1] = r; } r += v.y;
    if (base + 2 < N) { rowstart[base + 2] = r; wpos[base + 2] = r; } r += v.z;
    if (base + 3 < N) { rowstart[base + 3] = r; wpos[base + 3] = r; }
}

// Partitioned scatter (8 node-range partitions; see round-8 notes).
__global__ void k_scatter(const int* __restrict__ src, const int* __restrict__ tgt,
                          int* __restrict__ wpos, int* __restrict__ csr_src, int E,
                          int part_size) {
    const int part = blockIdx.x & 7;
    const int q = blockIdx.x >> 3;
    const int nq = gridDim.x >> 3;
    const int stride = nq * blockDim.x;
    for (int i = q * blockDim.x + threadIdx.x; i < E; i += stride) {
        const int tg = tgt[i];
        if (tg / part_size == part) {
            const int p = atomicAdd(&wpos[tg], 1);
            csr_src[p] = src[i];
        }
    }
}

// ---------------- per-node aggregation: out = sum(A[src])/max(deg,1) + B ----------------
template <bool RELU>
__global__ void k_aggr(const __hip_bfloat16* __restrict__ A,
                       const __hip_bfloat16* __restrict__ Bm,
                       const int* __restrict__ rowstart, const int* __restrict__ csr_src,
                       float* __restrict__ out, int N) {
    const int lane = threadIdx.x & 63;
    const int wave = blockIdx.x * (blockDim.x >> 6) + (threadIdx.x >> 6);
    const int nwaves = gridDim.x * (blockDim.x >> 6);
    for (int n = wave; n < N; n += nwaves) {
        const int r0 = rowstart[n];
        const int r1 = rowstart[n + 1];
        float s0 = 0.f, s1 = 0.f, s2 = 0.f, s3 = 0.f;
        int j = r0;
        for (; j + 3 < r1; j += 4) {
            const int c0 = csr_src[j];
            const int c1 = csr_src[j + 1];
            const int c2 = csr_src[j + 2];
            const int c3 = csr_src[j + 3];
            s0 += __bfloat162float(A[(size_t)c0 * DIM + lane]);
            s1 += __bfloat162float(A[(size_t)c1 * DIM + lane]);
            s2 += __bfloat162float(A[(size_t)c2 * DIM + lane]);
            s3 += __bfloat162float(A[(size_t)c3 * DIM + lane]);
        }
        for (; j < r1; ++j) s0 += __bfloat162float(A[(size_t)csr_src[j] * DIM + lane]);
        const float c = (float)(r1 - r0);
        float v = ((s0 + s1) + (s2 + s3)) / fmaxf(c, 1.f) +
                  __bfloat162float(Bm[(size_t)n * DIM + lane]);
        if (RELU) v = fmaxf(v, 0.f);
        out[(size_t)n * DIM + lane] = v;
    }
}

extern "C" void kernel_launch(void* const* d_in, const int* in_sizes, int n_in,
                              void* d_out, int out_size, void* d_ws, size_t ws_size,
                              hipStream_t stream) {
    const float* x   = (const float*)d_in[0];
    const int*   ei  = (const int*)d_in[1];
    const float* Wl1 = (const float*)d_in[2];
    const float* Wr1 = (const float*)d_in[3];
    const float* b1  = (const float*)d_in[4];
    const float* Wl2 = (const float*)d_in[5];
    const float* Wr2 = (const float*)d_in[6];
    const float* b2  = (const float*)d_in[7];
    float* out = (float*)d_out;

    const int N = in_sizes[0] / NFEAT;
    const int E = in_sizes[1] / 2;
    const int* src = ei;
    const int* tgt = ei + E;

    char* ws = (char*)d_ws;
    size_t off = 0;
    auto alloc = [&](size_t bytes) -> void* {
        void* p = ws + off;
        off = (off + bytes + 255) & ~(size_t)255;
        return p;
    };
    const int nb = (N + 1023) / 1024;
    int*   cnt      = (int*)alloc((size_t)N * 4);
    int*   rowstart = (int*)alloc((size_t)(N + 1) * 4);
    int*   wpos     = (int*)alloc((size_t)N * 4);
    int*   bsum     = (int*)alloc((size_t)nb * 4);
    int*   boff     = (int*)alloc((size_t)nb * 4);
    int*   csr      = (int*)alloc((size_t)E * 4);
    __hip_bfloat16* A = (__hip_bfloat16*)alloc((size_t)N * DIM * 2);
    __hip_bfloat16* B = (__hip_bfloat16*)alloc((size_t)N * DIM * 2);
    float* H        = (float*)alloc((size_t)N * DIM * 4);

    hipMemsetAsync(cnt, 0, (size_t)N * 4, stream);

    const int part_size = (N + 7) / 8;
    const int mm_blocks = (N + 31) / 32;
    const int mmB = (mm_blocks + 7) & ~7;  // round to x8 to keep hist bid&7 XCD-aligned
    const int histB = 2048;

    // fused: layer-1 mm (A1=x@Wl1, B1=x@Wr1+b1, bf16) + partitioned histogram
    k_mm_hist<NFEAT><<<mmB + histB, 256, 0, stream>>>(x, Wl1, Wr1, b1, A, B, N,
                                                      tgt, cnt, E, part_size, mmB);
    k_scan1<<<nb, 256, 0, stream>>>(cnt, bsum, N);
    k_scan2<<<1, 64, 0, stream>>>(bsum, boff, rowstart, nb, N);
    k_scan3<<<nb, 256, 0, stream>>>(cnt, boff, rowstart, wpos, N);
    k_scatter<<<2048, 256, 0, stream>>>(src, tgt, wpos, csr, E, part_size);

    // layer 1 aggregation: H = relu(aggr(A)/deg + B)
    k_aggr<true><<<2048, 256, 0, stream>>>(A, B, rowstart, csr, H, N);

    // layer 2: A = H@Wl2 (bf16), B = H@Wr2 + b2 (bf16); out = aggr(A)/deg + B
    k_mm<DIM><<<mm_blocks, 256, 0, stream>>>(H, Wl2, Wr2, b2, A, B, N);
    k_aggr<false><<<2048, 256, 0, stream>>>(A, B, rowstart, csr, out, N);
}